// Round 1
// 383.688 us; speedup vs baseline: 1.0552x; 1.0552x over previous
//
#include <hip/hip_runtime.h>
#include <cstdint>
#include <cstddef>

// DCNv2 x2 (B=2, C=O=256, H=W=96, k=3), fully fused per layer.
// R12: (1) hi/lo bf16 split precomputed ONCE (transpose kernel for x, dfconv
// L0 epilogue for h1) -> offconv staging is pure 16B copies, removing the 9x
// redundant per-tap fp32->bf16 split (~2.3e9 VALU ops). fp32 NHWC tensors
// dropped entirely (less write BW; d_out only written by L1 dfconv).
// (2) 2-deep register prefetch in offconv staging and dfconv producers:
// iteration k+1's global loads issue before iteration k's consumption, hiding
// L2 latency under compute. dfconv fences are now raw lgkmcnt(0) (LDS-only)
// so prefetched vmcnt loads survive the handoff.
// k' = kk*256 + c. XCD swizzle: blockIdx%8 = XCD.

#define KTOT 2304
#define PXB  9216

typedef __attribute__((ext_vector_type(8))) short bf16x8;
typedef __attribute__((ext_vector_type(4))) float f32x4;

static __device__ __forceinline__ unsigned short f2bf(float f) {
    union { float f; unsigned int u; } v; v.f = f;
    unsigned int r = (v.u + 0x7FFFu + ((v.u >> 16) & 1u)) >> 16;
    return (unsigned short)r;
}
static __device__ __forceinline__ float bf2f(unsigned short h) {
    union { unsigned int u; float f; } v; v.u = ((unsigned int)h) << 16;
    return v.f;
}
// unpack 8 bf16 (uint4) -> 8 fp32; 1 bit-op per element
static __device__ __forceinline__ void unpack8(uint4 u, float* f) {
    union { unsigned int u; float f; } t;
    t.u = u.x << 16;         f[0] = t.f;
    t.u = u.x & 0xffff0000u; f[1] = t.f;
    t.u = u.y << 16;         f[2] = t.f;
    t.u = u.y & 0xffff0000u; f[3] = t.f;
    t.u = u.z << 16;         f[4] = t.f;
    t.u = u.z & 0xffff0000u; f[5] = t.f;
    t.u = u.w << 16;         f[6] = t.f;
    t.u = u.w & 0xffff0000u; f[7] = t.f;
}

// ---------------------------------------------------------------------------
// NCHW -> NHWC transpose, hi/lo bf16 outputs (no fp32 NHWC anymore)
// ---------------------------------------------------------------------------
__global__ __launch_bounds__(256) void transpose_kernel(const float* __restrict__ in,
                                                        unsigned short* __restrict__ outH,
                                                        unsigned short* __restrict__ outL) {
    __shared__ float tile[64][65];
    const int hw0 = blockIdx.x * 64;
    const int c0  = blockIdx.y * 64;
    const int b   = blockIdx.z;
    const int lx  = threadIdx.x & 63;
    const int ly  = threadIdx.x >> 6;
#pragma unroll
    for (int i = 0; i < 16; ++i) {
        int cl = ly + i * 4;
        tile[cl][lx] = in[(size_t)(b * 256 + c0 + cl) * PXB + hw0 + lx];
    }
    __syncthreads();
#pragma unroll
    for (int i = 0; i < 16; ++i) {
        int hwl = ly + i * 4;
        float v = tile[lx][hwl];
        size_t oi = ((size_t)b * PXB + hw0 + hwl) * 256 + c0 + lx;
        unsigned short hi = f2bf(v);
        outH[oi] = hi;
        outL[oi] = f2bf(v - bf2f(hi));
    }
}

// ---------------------------------------------------------------------------
// Main weight prep: w[o][c][kk] fp32 -> wA[o][k'=kk*256+c] bf16
// ---------------------------------------------------------------------------
__global__ __launch_bounds__(256) void prep_w_kernel(const float* __restrict__ w,
                                                     unsigned short* __restrict__ wA) {
    int idx = blockIdx.x * 256 + threadIdx.x;   // 256*2304
    int o = idx / KTOT;
    int k = idx - o * KTOT;
    int kk = k >> 8;
    int c  = k & 255;
    wA[idx] = f2bf(w[o * KTOT + c * 9 + kk]);
}

// ---------------------------------------------------------------------------
// Offset weight prep (split): rows 27..32 zero. hi = bf16(w), lo = bf16(w-hi).
// ---------------------------------------------------------------------------
__global__ __launch_bounds__(256) void prep_woff_kernel(const float* __restrict__ w,
                                                        unsigned short* __restrict__ wH,
                                                        unsigned short* __restrict__ wL) {
    int idx = blockIdx.x * 256 + threadIdx.x;   // 32*2304
    int o = idx / KTOT;
    int k = idx - o * KTOT;
    int kk = k >> 8;
    int c  = k & 255;
    float f = (o < 27) ? w[o * KTOT + c * 9 + kk] : 0.0f;
    unsigned short hi = f2bf(f);
    wH[idx] = hi;
    wL[idx] = f2bf(f - bf2f(hi));
}

// ---------------------------------------------------------------------------
// Fused offset conv: M=32(27) x N=64px x K=2304, split-bf16 3-term.
// Grid 288 x 512 threads; waves 0-3 K-half0, waves 4-7 K-half1.
// R12: B source is precomputed hi/lo bf16 NHWC (no conversion in staging);
// A+B panels for it+1 prefetched into registers during it's MFMA phase.
// ---------------------------------------------------------------------------
__global__ __launch_bounds__(512) void offconv_fused(const unsigned short* __restrict__ xH,
                                                     const unsigned short* __restrict__ xL,
                                                     const unsigned short* __restrict__ AH,
                                                     const unsigned short* __restrict__ AL,
                                                     const float* __restrict__ bias,
                                                     float* __restrict__ om) {
    __shared__ __attribute__((aligned(16))) unsigned short AsH[2][32 * 72];
    __shared__ __attribute__((aligned(16))) unsigned short AsL[2][32 * 72];
    __shared__ __attribute__((aligned(16))) unsigned short BsH[2][64 * 72];
    __shared__ __attribute__((aligned(16))) unsigned short BsL[2][64 * 72];

    const int tid  = threadIdx.x;
    const int kg   = tid >> 8;
    const int tl   = tid & 255;
    const int lane = tid & 63;
    const int wq   = (tid >> 6) & 3;
    const int quad = lane >> 4, l16 = lane & 15;
    const int g    = blockIdx.x;            // 288
    const int nb   = (g & 7) * 36 + (g >> 3);
    const int n0   = nb * 64;
    const int b    = n0 / PXB;
    const int hw0  = n0 - b * PXB;

    f32x4 acc[2];
#pragma unroll
    for (int mt = 0; mt < 2; ++mt) acc[mt] = (f32x4)0.0f;

    const int arow = tl >> 3, akg = tl & 7;

    // prefetch registers (A panel + 2 B tasks, hi/lo)
    uint4 pAH, pAL, pBH0, pBL0, pBH1, pBL1;
    auto pf = [&](int it) {
        const int kt = kg * 18 + it;
        const int kk = kt >> 2, c0 = (kt & 3) * 64;
        const int dy = kk / 3 - 1, dx = kk - (kk / 3) * 3 - 1;
        size_t ai = (size_t)arow * KTOT + kt * 64 + akg * 8;
        pAH = *(const uint4*)&AH[ai];
        pAL = *(const uint4*)&AL[ai];
#pragma unroll
        for (int i = 0; i < 2; ++i) {
            int task = i * 256 + tl;
            int px = task >> 3, cg = task & 7;
            int hw = hw0 + px;
            int h = hw / 96, w = hw - h * 96;
            int y = h + dy, x = w + dx;
            uint4 hv = make_uint4(0u, 0u, 0u, 0u), lv = make_uint4(0u, 0u, 0u, 0u);
            if (((unsigned)y < 96u) && ((unsigned)x < 96u)) {
                size_t bi = ((size_t)b * PXB + y * 96 + x) * 256 + c0 + cg * 8;
                hv = *(const uint4*)&xH[bi];
                lv = *(const uint4*)&xL[bi];
            }
            if (i == 0) { pBH0 = hv; pBL0 = lv; } else { pBH1 = hv; pBL1 = lv; }
        }
    };
    pf(0);

    for (int it = 0; it < 18; ++it) {
        __syncthreads();
        // write staged registers to LDS
        *(uint4*)&AsH[kg][arow * 72 + akg * 8] = pAH;
        *(uint4*)&AsL[kg][arow * 72 + akg * 8] = pAL;
        {
            int px = tl >> 3, cg = tl & 7;
            *(uint4*)&BsH[kg][px * 72 + cg * 8] = pBH0;
            *(uint4*)&BsL[kg][px * 72 + cg * 8] = pBL0;
        }
        {
            int task = 256 + tl;
            int px = task >> 3, cg = task & 7;
            *(uint4*)&BsH[kg][px * 72 + cg * 8] = pBH1;
            *(uint4*)&BsL[kg][px * 72 + cg * 8] = pBL1;
        }
        // issue next iteration's loads; latency hides under MFMA phase below
        if (it < 17) pf(it + 1);
        __syncthreads();
#pragma unroll
        for (int ks = 0; ks < 2; ++ks) {
            bf16x8 ah[2], al[2], bh, bl;
#pragma unroll
            for (int mt = 0; mt < 2; ++mt) {
                ah[mt] = *(const bf16x8*)&AsH[kg][(mt * 16 + l16) * 72 + ks * 32 + quad * 8];
                al[mt] = *(const bf16x8*)&AsL[kg][(mt * 16 + l16) * 72 + ks * 32 + quad * 8];
            }
            bh = *(const bf16x8*)&BsH[kg][(wq * 16 + l16) * 72 + ks * 32 + quad * 8];
            bl = *(const bf16x8*)&BsL[kg][(wq * 16 + l16) * 72 + ks * 32 + quad * 8];
#pragma unroll
            for (int mt = 0; mt < 2; ++mt) {
                acc[mt] = __builtin_amdgcn_mfma_f32_16x16x32_bf16(ah[mt], bh, acc[mt], 0, 0, 0);
                acc[mt] = __builtin_amdgcn_mfma_f32_16x16x32_bf16(ah[mt], bl, acc[mt], 0, 0, 0);
                acc[mt] = __builtin_amdgcn_mfma_f32_16x16x32_bf16(al[mt], bh, acc[mt], 0, 0, 0);
            }
        }
    }

    // ---- in-block split-K reduction: kg1 publishes, kg0 adds + stores ----
    float* red = (float*)BsH;
    __syncthreads();
    if (kg == 1) {
#pragma unroll
        for (int mt = 0; mt < 2; ++mt)
#pragma unroll
            for (int r = 0; r < 4; ++r)
                red[wq * 512 + mt * 256 + quad * 64 + r * 16 + l16] = acc[mt][r];
    }
    __syncthreads();
    if (kg == 0) {
#pragma unroll
        for (int mt = 0; mt < 2; ++mt)
#pragma unroll
            for (int r = 0; r < 4; ++r) {
                float v = acc[mt][r] + red[wq * 512 + mt * 256 + quad * 64 + r * 16 + l16];
                int m = mt * 16 + quad * 4 + r;
                int n = wq * 16 + l16;
                if (m < 27)
                    om[(size_t)(b * 27 + m) * PXB + hw0 + n] = v + bias[m];
            }
    }
}

// ---------------------------------------------------------------------------
// Fused deformable conv, producer/consumer: M=256 x N=32px, K=2304.
// Grid 576 x 512 thr. Waves 0-3 gather (bf16 source, 4x16B loads/cell) into
// a 4-deep LDS ring; waves 4-7 consume with MFMA (A direct from L2).
// R12: producers prefetch kt+1's 4 corner loads before consuming kt's (2-deep
// register pipeline); fences are lgkmcnt(0)-only so prefetch stays in flight.
// out_mode 0: NCHW fp32. out_mode 1: NHWC hi/lo bf16 (outH/outL).
// ---------------------------------------------------------------------------
__global__ __launch_bounds__(512) void dfconv_fused(const unsigned short* __restrict__ xB,
                                                    const float* __restrict__ om,
                                                    const unsigned short* __restrict__ A,
                                                    float* __restrict__ out,
                                                    unsigned short* __restrict__ outH,
                                                    unsigned short* __restrict__ outL,
                                                    int out_mode) {
    __shared__ __attribute__((aligned(16))) unsigned short Bs[4][32 * 72]; // ring 18.4 KB
    __shared__ __attribute__((aligned(16))) unsigned short goff[288 * 4];
    __shared__ __attribute__((aligned(16))) float gwt[288 * 4];
    __shared__ int ready[4];
    __shared__ int done[4];

    const int tid  = threadIdx.x;
    const int wv   = tid >> 6;
    const int lane = tid & 63;
    const int quad = lane >> 4, l16 = lane & 15;
    // XCD swizzle: g%8 = xcd owns n-blocks [xcd*72, xcd*72+72)
    const int g    = blockIdx.x;            // 576
    const int nb   = (g & 7) * 72 + (g >> 3);
    const int n0   = nb * 32;
    const int b    = n0 / PXB;
    const int hw0  = n0 - b * PXB;

    if (tid < 4) { ready[tid] = 0; done[tid] = 0; }

    // ---- geometry: 32 px x 9 taps ----
    if (tid < 288) {
        int task = tid;
        int px = task / 9;
        int kk = task - px * 9;
        int hw = hw0 + px;
        int h = hw / 96, w = hw - h * 96;
        const float* omp = om + (size_t)b * 27 * PXB + hw;
        float dyv = omp[(size_t)(2 * kk) * PXB];
        float dxv = omp[(size_t)(2 * kk + 1) * PXB];
        float mv  = omp[(size_t)(18 + kk) * PXB];
        float mk  = 1.0f / (1.0f + __expf(-mv));

        float ys = (float)(h + (kk / 3) - 1) + dyv;
        float xs = (float)(w + (kk - (kk / 3) * 3) - 1) + dxv;
        float fy = floorf(ys), fx = floorf(xs);
        int iy = (int)fy, ix = (int)fx;
        float wy1 = ys - fy, wx1 = xs - fx;
        float wy0 = 1.0f - wy1, wx0 = 1.0f - wx1;
        bool yv0 = (unsigned)iy < 96u, yv1 = (unsigned)(iy + 1) < 96u;
        bool xv0 = (unsigned)ix < 96u, xv1 = (unsigned)(ix + 1) < 96u;
        int y0 = min(max(iy, 0), 95),     y1 = min(max(iy + 1, 0), 95);
        int x0 = min(max(ix, 0), 95),     x1 = min(max(ix + 1, 0), 95);
        int gg = task * 4;
        goff[gg + 0] = (unsigned short)(y0 * 96 + x0);
        goff[gg + 1] = (unsigned short)(y0 * 96 + x1);
        goff[gg + 2] = (unsigned short)(y1 * 96 + x0);
        goff[gg + 3] = (unsigned short)(y1 * 96 + x1);
        gwt[gg + 0] = (yv0 && xv0) ? mk * wy0 * wx0 : 0.0f;
        gwt[gg + 1] = (yv0 && xv1) ? mk * wy0 * wx1 : 0.0f;
        gwt[gg + 2] = (yv1 && xv0) ? mk * wy1 * wx0 : 0.0f;
        gwt[gg + 3] = (yv1 && xv1) ? mk * wy1 * wx1 : 0.0f;
    }
    __syncthreads();   // geometry + flags visible

    volatile int* vready = ready;
    volatile int* vdone  = done;

    f32x4 acc[4][2];
#pragma unroll
    for (int mt = 0; mt < 4; ++mt) { acc[mt][0] = (f32x4)0.0f; acc[mt][1] = (f32x4)0.0f; }

    if (wv < 4) {
        // ================= PRODUCERS (waves 0-3) =================
        const int pl = wv * 64 + lane;      // 0..255: cell id
        const int px = pl >> 3, cg = pl & 7;
        const unsigned short* xbase = xB + (size_t)b * PXB * 256 + cg * 8;

        // prefetch kt = 0
        uint4 ua0, ua1, ua2, ua3; float4 wta;
        {
            int gg = (px * 9 + 0) * 4;
            ushort4 o4 = *(const ushort4*)&goff[gg];
            wta = *(const float4*)&gwt[gg];
            ua0 = *(const uint4*)(xbase + (size_t)o4.x * 256);
            ua1 = *(const uint4*)(xbase + (size_t)o4.y * 256);
            ua2 = *(const uint4*)(xbase + (size_t)o4.z * 256);
            ua3 = *(const uint4*)(xbase + (size_t)o4.w * 256);
        }
        for (int kt = 0; kt < 36; ++kt) {
            const int st = kt & 3, rr = kt >> 2;
            // issue kt+1's corner loads (clamped; last iter redundant-loads kt=35)
            const int kn = (kt < 35) ? kt + 1 : 35;
            const int tapn = kn >> 2, c0n = (kn & 3) * 64;
            uint4 ub0, ub1, ub2, ub3; float4 wtb;
            {
                int gg = (px * 9 + tapn) * 4;
                ushort4 o4 = *(const ushort4*)&goff[gg];
                wtb = *(const float4*)&gwt[gg];
                const unsigned short* cb = xbase + c0n;
                ub0 = *(const uint4*)(cb + (size_t)o4.x * 256);
                ub1 = *(const uint4*)(cb + (size_t)o4.y * 256);
                ub2 = *(const uint4*)(cb + (size_t)o4.z * 256);
                ub3 = *(const uint4*)(cb + (size_t)o4.w * 256);
            }
            // wait for consumers to release this slot (round rr-1)
            const int tgt = 4 * rr;
            while (vdone[st] < tgt) __builtin_amdgcn_s_sleep(1);
            // unpack + interp + convert + write panel (consumes kt's regs)
            float f0[8], f1[8], f2[8], f3[8];
            unpack8(ua0, f0); unpack8(ua1, f1); unpack8(ua2, f2); unpack8(ua3, f3);
            unsigned short res[8];
#pragma unroll
            for (int j = 0; j < 8; ++j)
                res[j] = f2bf(wta.x * f0[j] + wta.y * f1[j] + wta.z * f2[j] + wta.w * f3[j]);
            *(uint4*)&Bs[st][px * 72 + cg * 8] = *(uint4*)res;
            // LDS-only fence: do NOT drain vmcnt (prefetched loads in flight)
            asm volatile("s_waitcnt lgkmcnt(0)" ::: "memory");
            if (lane == 0) atomicAdd(&ready[st], 1);
            ua0 = ub0; ua1 = ub1; ua2 = ub2; ua3 = ub3; wta = wtb;
        }
    } else {
        // ================= CONSUMERS (waves 4-7) =================
        const int mq = wv - 4;
        const unsigned short* Arow = A + (size_t)(mq * 64 + l16) * KTOT + quad * 8;

        for (int kt = 0; kt < 36; ++kt) {
            const int st = kt & 3, rr = kt >> 2;
            bf16x8 af[2][4];
#pragma unroll
            for (int ks = 0; ks < 2; ++ks)
#pragma unroll
                for (int mt = 0; mt < 4; ++mt)
                    af[ks][mt] = *(const bf16x8*)(Arow + (size_t)(mt * 16) * KTOT + kt * 64 + ks * 32);
            const int tgt = 4 * (rr + 1);
            while (vready[st] < tgt) __builtin_amdgcn_s_sleep(1);
#pragma unroll
            for (int ks = 0; ks < 2; ++ks) {
                bf16x8 bfr[2];
#pragma unroll
                for (int nt = 0; nt < 2; ++nt)
                    bfr[nt] = *(const bf16x8*)&Bs[st][(nt * 16 + l16) * 72 + ks * 32 + quad * 8];
#pragma unroll
                for (int mt = 0; mt < 4; ++mt)
#pragma unroll
                    for (int nt = 0; nt < 2; ++nt)
                        acc[mt][nt] = __builtin_amdgcn_mfma_f32_16x16x32_bf16(
                            af[ks][mt], bfr[nt], acc[mt][nt], 0, 0, 0);
            }
            // LDS-only fence: bfr ds_reads complete -> slot reusable
            asm volatile("s_waitcnt lgkmcnt(0)" ::: "memory");
            if (lane == 0) atomicAdd(&done[st], 1);
        }
    }

    __syncthreads();   // join for epilogue

    // ---- epilogues: staging aliases the Bs ring ----
    float* tileS = (float*)Bs;   // 18432 B
    if (out_mode == 0) {
        // NCHW out[b][m][hw0..+31]: 2 passes of 128 m; tileS[128][36]
#pragma unroll
        for (int pass = 0; pass < 2; ++pass) {
            if (wv >= 4 && (wv - 4) >> 1 == pass) {
                int mqh = (wv - 4) & 1;
#pragma unroll
                for (int mt = 0; mt < 4; ++mt)
#pragma unroll
                    for (int nt = 0; nt < 2; ++nt)
#pragma unroll
                        for (int r = 0; r < 4; ++r) {
                            int ml = mqh * 64 + mt * 16 + quad * 4 + r;   // 0..127
                            int n  = nt * 16 + l16;                        // 0..31
                            tileS[ml * 36 + n] = fmaxf(acc[mt][nt][r], 0.0f);
                        }
            }
            __syncthreads();
#pragma unroll
            for (int j = 0; j < 2; ++j) {
                int idx = j * 512 + tid;          // 1024 float4s = 128m x 8q
                int row = idx >> 3, q = idx & 7;
                int m = pass * 128 + row;
                *(float4*)&out[(size_t)(b * 256 + m) * PXB + hw0 + q * 4] =
                    *(const float4*)&tileS[row * 36 + q * 4];
            }
            __syncthreads();
        }
    } else {
        // NHWC hi/lo bf16 (outH/outL): 2 passes of 16 px.
#pragma unroll
        for (int pass = 0; pass < 2; ++pass) {
            if (wv >= 4) {
                int mq = wv - 4;
#pragma unroll
                for (int mt = 0; mt < 4; ++mt) {
                    f32x4 v = acc[mt][pass];
                    v[0] = fmaxf(v[0], 0.f); v[1] = fmaxf(v[1], 0.f);
                    v[2] = fmaxf(v[2], 0.f); v[3] = fmaxf(v[3], 0.f);
                    *(f32x4*)&tileS[l16 * 264 + mq * 64 + mt * 16 + quad * 4] = v;
                }
            }
            __syncthreads();
#pragma unroll
            for (int j = 0; j < 2; ++j) {
                int idx = j * 512 + tid;          // 1024 float4s = 16px x 64
                int pxl = idx >> 6, ln = idx & 63;
                float4 v = *(const float4*)&tileS[pxl * 264 + ln * 4];
                size_t oi = ((size_t)b * PXB + hw0 + pass * 16 + pxl) * 256 + ln * 4;
                unsigned short hv[4], lv[4];
#pragma unroll
                for (int e = 0; e < 4; ++e) {
                    float fe = (e == 0) ? v.x : (e == 1) ? v.y : (e == 2) ? v.z : v.w;
                    hv[e] = f2bf(fe);
                    lv[e] = f2bf(fe - bf2f(hv[e]));
                }
                *(ushort4*)&outH[oi] = *(ushort4*)hv;
                *(ushort4*)&outL[oi] = *(ushort4*)lv;
            }
            __syncthreads();
        }
    }
}

// ---------------------------------------------------------------------------
extern "C" void kernel_launch(void* const* d_in, const int* in_sizes, int n_in,
                              void* d_out, int out_size, void* d_ws, size_t ws_size,
                              hipStream_t stream) {
    const float* x     = (const float*)d_in[0];
    const float* woff0 = (const float*)d_in[1];
    const float* boff0 = (const float*)d_in[2];
    const float* w0    = (const float*)d_in[3];
    const float* woff1 = (const float*)d_in[4];
    const float* boff1 = (const float*)d_in[5];
    const float* w1    = (const float*)d_in[6];
    float* out = (float*)d_out;

    char* p = (char*)d_ws;
    float* om  = (float*)p;  p += (size_t)2 * 27 * PXB * 4;               // 2.0 MB
    unsigned short* xh  = (unsigned short*)p; p += (size_t)2 * 256 * PXB * 2;  // 9.4 MB
    unsigned short* xl  = (unsigned short*)p; p += (size_t)2 * 256 * PXB * 2;  // 9.4 MB
    unsigned short* h1h = (unsigned short*)p; p += (size_t)2 * 256 * PXB * 2;  // 9.4 MB
    unsigned short* h1l = (unsigned short*)p; p += (size_t)2 * 256 * PXB * 2;  // 9.4 MB
    unsigned short* wA0 = (unsigned short*)p; p += (size_t)256 * KTOT * 2;
    unsigned short* wA1 = (unsigned short*)p; p += (size_t)256 * KTOT * 2;
    unsigned short* wH0 = (unsigned short*)p; p += (size_t)32 * KTOT * 2;
    unsigned short* wL0 = (unsigned short*)p; p += (size_t)32 * KTOT * 2;
    unsigned short* wH1 = (unsigned short*)p; p += (size_t)32 * KTOT * 2;
    unsigned short* wL1 = (unsigned short*)p; p += (size_t)32 * KTOT * 2;

    hipLaunchKernelGGL(transpose_kernel, dim3(PXB / 64, 4, 2), dim3(256), 0, stream, x, xh, xl);
    hipLaunchKernelGGL(prep_w_kernel, dim3(256 * KTOT / 256), dim3(256), 0, stream, w0, wA0);
    hipLaunchKernelGGL(prep_w_kernel, dim3(256 * KTOT / 256), dim3(256), 0, stream, w1, wA1);
    hipLaunchKernelGGL(prep_woff_kernel, dim3(32 * KTOT / 256), dim3(256), 0, stream, woff0, wH0, wL0);
    hipLaunchKernelGGL(prep_woff_kernel, dim3(32 * KTOT / 256), dim3(256), 0, stream, woff1, wH1, wL1);

    // Layer 0: x -> h1 (hi/lo bf16 NHWC in workspace)
    hipLaunchKernelGGL(offconv_fused, dim3(288), dim3(512), 0, stream, xh, xl, wH0, wL0, boff0, om);
    hipLaunchKernelGGL(dfconv_fused, dim3(576), dim3(512), 0, stream, xh, om, wA0,
                       (float*)nullptr, h1h, h1l, 1);

    // Layer 1: h1 -> out (NCHW fp32)
    hipLaunchKernelGGL(offconv_fused, dim3(288), dim3(512), 0, stream, h1h, h1l, wH1, wL1, boff1, om);
    hipLaunchKernelGGL(dfconv_fused, dim3(576), dim3(512), 0, stream, h1h, om, wA1,
                       out, (unsigned short*)nullptr, (unsigned short*)nullptr, 0);
}